// Round 5
// baseline (1056.019 us; speedup 1.0000x reference)
//
#include <hip/hip_runtime.h>
#include <hip/hip_bf16.h>

#define N_NODES 50000
#define E_EDGES 200000
static constexpr float INV_SQRT_C = 0.08838834764831845f; // 1/sqrt(128)

typedef __attribute__((ext_vector_type(4))) float f32x4;
typedef __attribute__((ext_vector_type(8))) short s16x8;
typedef __attribute__((ext_vector_type(4))) short s16x4;

__device__ __forceinline__ float b2f(unsigned short u) {
  union { unsigned u; float f; } x; x.u = ((unsigned)u) << 16; return x.f;
}
__device__ __forceinline__ short f2b(float f) {
  union { float f; unsigned u; } x; x.f = f;
  unsigned r = x.u + 0x7FFFu + ((x.u >> 16) & 1u);  // RNE
  return (short)(r >> 16);
}

struct WPtrs { const float* w[10]; };

// Repack 10 [256x256] f32 weights into bf16 MFMA-fragment order:
//   out[((ct*8 + ks)*16 + colb)*32 + g*8 + j] = W[ks*32 + g*8 + j][ct*16 + colb]
// so a wave's B-fragment load (lane = colb + 16*g) reads a dense 1KB block.
// Grid 40: block = (weight, 64-col quarter). LDS bounce keeps both global
// sides coalesced.
__global__ __launch_bounds__(256) void prep_transpose(WPtrs p, short* __restrict__ out) {
  __shared__ short T[256 * 66];              // [k][cc], pad 66 (stride 33 words)
  const int wi = blockIdx.x >> 2, cq = blockIdx.x & 3;
  const float* w = p.w[wi];
  short* o = out + wi * 65536;
  const int tid = threadIdx.x;
#pragma unroll
  for (int i = 0; i < 64; ++i) {             // coalesced f32 reads
    int flat = tid + i * 256;
    int k = flat >> 6, cc = flat & 63;
    T[k * 66 + cc] = f2b(w[k * 256 + cq * 64 + cc]);
  }
  __syncthreads();
#pragma unroll
  for (int i = 0; i < 8; ++i) {              // coalesced 16B fragment stores
    int flat2 = tid + i * 256;
    int g = flat2 & 3, colb = (flat2 >> 2) & 15, ks = (flat2 >> 6) & 7, ctl = flat2 >> 9;
    int ct = cq * 4 + ctl;
    s16x8 v;
#pragma unroll
    for (int j = 0; j < 8; ++j)
      v[j] = T[(ks * 32 + g * 8 + j) * 66 + ctl * 16 + colb];
    *(s16x8*)(o + (((ct * 8 + ks) * 16 + colb) * 32 + g * 8)) = v;
  }
}

// ---------------- node GEMM v3 ----------------
// 512 thr / 8 waves, 64 rows per block, wave owns 32 cols (2 ct).
// Per job: preload all 16 B fragments (dense coalesced loads, single drain),
// then pure LDS+MFMA inner loop. Int-only epilogue with uniform block guard.
__global__ __launch_bounds__(512, 4) void node_gemm3(
    const float* __restrict__ X, int M,
    const short* __restrict__ Wt0, const float* __restrict__ bias0,
    unsigned short* __restrict__ o16_0, float* __restrict__ of0,
    const short* __restrict__ Wt1, const float* __restrict__ bias1,
    unsigned short* __restrict__ o16_1, float* __restrict__ of1)
{
  __shared__ short As[64 * 264];
  const int tid = threadIdx.x;
  const int l = tid & 63;
  const int w = tid >> 6;
  const int m0 = blockIdx.x * 64;
  const bool fullblk = (m0 + 64 <= M);

  if (fullblk) {
#pragma unroll
    for (int i = 0; i < 8; ++i) {
      int flat = tid + i * 512;
      int r = flat >> 6, c4 = flat & 63;
      float4 xv = *(const float4*)(X + (size_t)(m0 + r) * 256 + c4 * 4);
      s16x4 sv; sv[0] = f2b(xv.x); sv[1] = f2b(xv.y); sv[2] = f2b(xv.z); sv[3] = f2b(xv.w);
      *(s16x4*)&As[r * 264 + c4 * 4] = sv;
    }
  } else {
#pragma unroll
    for (int i = 0; i < 8; ++i) {
      int flat = tid + i * 512;
      int r = flat >> 6, c4 = flat & 63;
      float4 xv = make_float4(0.f, 0.f, 0.f, 0.f);
      if (m0 + r < M) xv = *(const float4*)(X + (size_t)(m0 + r) * 256 + c4 * 4);
      s16x4 sv; sv[0] = f2b(xv.x); sv[1] = f2b(xv.y); sv[2] = f2b(xv.z); sv[3] = f2b(xv.w);
      *(s16x4*)&As[r * 264 + c4 * 4] = sv;
    }
  }
  __syncthreads();

  const int colb = l & 15;
  const int g = l >> 4;
  const int arow4 = g * 4;

#pragma unroll 1
  for (int job = 0; job < 2; ++job) {
    const short* Wt = job ? Wt1 : Wt0;
    const float* bias = job ? bias1 : bias0;
    unsigned short* o16 = job ? o16_1 : o16_0;
    float* of = job ? of1 : of0;

    s16x8 b[2][8];
#pragma unroll
    for (int ks = 0; ks < 8; ++ks) {
      b[0][ks] = *(const s16x8*)(Wt + (((2 * w + 0) * 8 + ks) * 16 + colb) * 32 + g * 8);
      b[1][ks] = *(const s16x8*)(Wt + (((2 * w + 1) * 8 + ks) * 16 + colb) * 32 + g * 8);
    }
    f32x4 acc[4][2];
#pragma unroll
    for (int m = 0; m < 4; ++m) { acc[m][0] = (f32x4)(0.0f); acc[m][1] = (f32x4)(0.0f); }
#pragma unroll
    for (int ks = 0; ks < 8; ++ks)
#pragma unroll
      for (int m = 0; m < 4; ++m) {
        s16x8 a = *(const s16x8*)&As[(16 * m + colb) * 264 + ks * 32 + g * 8];
        acc[m][0] = __builtin_amdgcn_mfma_f32_16x16x32_bf16(a, b[0][ks], acc[m][0], 0, 0, 0);
        acc[m][1] = __builtin_amdgcn_mfma_f32_16x16x32_bf16(a, b[1][ks], acc[m][1], 0, 0, 0);
      }

    if (of) {
#pragma unroll
      for (int j = 0; j < 2; ++j) {
        int col = (2 * w + j) * 16 + colb;
        float bv = bias[col];
#pragma unroll
        for (int m = 0; m < 4; ++m) {
          int rb = m0 + 16 * m + arow4;
#pragma unroll
          for (int r = 0; r < 4; ++r)
            if (fullblk || rb + r < M) of[(size_t)(rb + r) * 256 + col] = acc[m][j][r] + bv;
        }
      }
    } else {
#pragma unroll
      for (int j = 0; j < 2; ++j) {
        int col = (2 * w + j) * 16 + colb;
        float bv = bias[col];
#pragma unroll
        for (int m = 0; m < 4; ++m) {
          int rb = m0 + 16 * m + arow4;
#pragma unroll
          for (int r = 0; r < 4; ++r)
            if (fullblk || rb + r < M)
              o16[(size_t)(rb + r) * 256 + col] = (unsigned short)f2b(acc[m][j][r] + bv);
        }
      }
    }
  }
}

// ---------------- CSR build ----------------
__global__ __launch_bounds__(256) void csr_count(const int* __restrict__ ei, int* __restrict__ counts) {
  int t = blockIdx.x * 256 + threadIdx.x;
  if (t < E_EDGES) atomicAdd(&counts[ei[E_EDGES + t]], 1);
}

__global__ __launch_bounds__(1024) void csr_scan(const int* __restrict__ counts,
                                                 int* __restrict__ start,
                                                 int* __restrict__ cursor, int n) {
  __shared__ int wsum[16];
  __shared__ int chunk_tot;
  __shared__ int carry_s;
  const int tid = threadIdx.x, lane = tid & 63, wid = tid >> 6;
  if (tid == 0) carry_s = 0;
  __syncthreads();
  for (int base = 0; base < n; base += 1024) {
    int gi = base + tid;
    int x = (gi < n) ? counts[gi] : 0;
    int v = x;
#pragma unroll
    for (int d = 1; d < 64; d <<= 1) {
      int t = __shfl_up(v, d);
      if (lane >= d) v += t;
    }
    if (lane == 63) wsum[wid] = v;
    __syncthreads();
    if (tid == 0) {
      int run = 0;
#pragma unroll
      for (int i = 0; i < 16; ++i) { int t = wsum[i]; wsum[i] = run; run += t; }
      chunk_tot = run;
    }
    __syncthreads();
    if (gi < n) {
      int excl = carry_s + wsum[wid] + v - x;
      start[gi] = excl;
      cursor[gi] = excl;
    }
    __syncthreads();
    if (tid == 0) carry_s += chunk_tot;
  }
  if (tid == 0) start[n] = carry_s;
}

__global__ __launch_bounds__(256) void csr_fill(const int* __restrict__ ei,
                                                int* __restrict__ cursor,
                                                int* __restrict__ eidx, int* __restrict__ esrc) {
  int t = blockIdx.x * 256 + threadIdx.x;
  if (t < E_EDGES) {
    int d = ei[E_EDGES + t];
    int p = atomicAdd(&cursor[d], 1);
    eidx[p] = t;
    esrc[p] = ei[t];
  }
}

// ---------------- edge GEMM v3: e16 = [cos(rel*Wt+bt) | msg] @ We ----------------
// B preloaded (dense fragments) right after staging issue so its latency
// hides under the cos/cvt phase; MFMA inner loop is pure LDS.
__global__ __launch_bounds__(512, 4) void edge_gemm3(
    const int* __restrict__ ei, const float* __restrict__ tvec,
    const float* __restrict__ lu, const float* __restrict__ msg,
    const float* __restrict__ Wtim, const float* __restrict__ btim,
    const short* __restrict__ WeT, unsigned short* __restrict__ e16g)
{
  __shared__ short attr[64 * 264];
  __shared__ float rel[64];

  const int tid = threadIdx.x;
  const int l = tid & 63;
  const int w = tid >> 6;
  const int e0 = blockIdx.x * 64;
  const int colb = l & 15;
  const int g = l >> 4;

  const float wt = Wtim[tid & 127], bt = btim[tid & 127];

  if (tid < 64) rel[tid] = tvec[e0 + tid] - lu[ei[e0 + tid]];
#pragma unroll
  for (int i = 0; i < 4; ++i) {
    int flat = tid + i * 512;
    int row = flat >> 5, c4 = flat & 31;
    float4 mv = *(const float4*)(msg + (size_t)(e0 + row) * 128 + c4 * 4);
    s16x4 sv; sv[0] = f2b(mv.x); sv[1] = f2b(mv.y); sv[2] = f2b(mv.z); sv[3] = f2b(mv.w);
    *(s16x4*)&attr[row * 264 + 128 + c4 * 4] = sv;
  }
  __syncthreads();   // rel + msg staged

  // preload B fragments now; latency hides under the cos phase below
  s16x8 b[2][8];
#pragma unroll
  for (int ks = 0; ks < 8; ++ks) {
    b[0][ks] = *(const s16x8*)(WeT + (((2 * w + 0) * 8 + ks) * 16 + colb) * 32 + g * 8);
    b[1][ks] = *(const s16x8*)(WeT + (((2 * w + 1) * 8 + ks) * 16 + colb) * 32 + g * 8);
  }

  { // time-encoder cols: fixed col per thread, 16 rows each
    int col = tid & 127;
    int r0 = (tid >> 7) * 16;
#pragma unroll
    for (int i = 0; i < 16; ++i)
      attr[(r0 + i) * 264 + col] = f2b(__cosf(rel[r0 + i] * wt + bt));
  }
  __syncthreads();

  f32x4 acc[4][2];
#pragma unroll
  for (int m = 0; m < 4; ++m) { acc[m][0] = (f32x4)(0.0f); acc[m][1] = (f32x4)(0.0f); }
#pragma unroll
  for (int ks = 0; ks < 8; ++ks)
#pragma unroll
    for (int m = 0; m < 4; ++m) {
      s16x8 a = *(const s16x8*)&attr[(16 * m + colb) * 264 + ks * 32 + g * 8];
      acc[m][0] = __builtin_amdgcn_mfma_f32_16x16x32_bf16(a, b[0][ks], acc[m][0], 0, 0, 0);
      acc[m][1] = __builtin_amdgcn_mfma_f32_16x16x32_bf16(a, b[1][ks], acc[m][1], 0, 0, 0);
    }
  __syncthreads();   // all waves done reading attr
#pragma unroll
  for (int j = 0; j < 2; ++j)
#pragma unroll
    for (int m = 0; m < 4; ++m)
#pragma unroll
      for (int r = 0; r < 4; ++r)
        attr[(16 * m + g * 4 + r) * 264 + (2 * w + j) * 16 + colb] = f2b(acc[m][j][r]);
  __syncthreads();

  // stream e (bf16) to global, coalesced 16B stores
#pragma unroll
  for (int i = 0; i < 4; ++i) {
    int flat = tid + i * 512;
    int row = flat >> 5, cg = flat & 31;
    *(s16x8*)(e16g + (size_t)(e0 + row) * 256 + cg * 8) = *(const s16x8*)&attr[row * 264 + cg * 8];
  }
}

// ---------------- fused aggregate: one wave per dst node ----------------
__global__ __launch_bounds__(256) void aggregate_fused(
    const int* __restrict__ start, const int* __restrict__ eidx, const int* __restrict__ esrc,
    const unsigned short* __restrict__ Q16, const unsigned short* __restrict__ K16,
    const unsigned short* __restrict__ V16, const unsigned short* __restrict__ e16,
    float* __restrict__ out)
{
  const int d = blockIdx.x * 4 + (threadIdx.x >> 6);
  if (d >= N_NODES) return;
  const int lane = threadIdx.x & 63;
  const int s0 = start[d], s1 = start[d + 1];
  if (s1 <= s0) return;
  const int c0 = lane * 4;          // lanes 0-31: head 0; 32-63: head 1

  s16x4 qv = *(const s16x4*)(Q16 + (size_t)d * 256 + c0);
  const float q0 = b2f((unsigned short)qv[0]), q1 = b2f((unsigned short)qv[1]);
  const float q2 = b2f((unsigned short)qv[2]), q3 = b2f((unsigned short)qv[3]);

  float den = 0.f;
  float acc0 = 0.f, acc1 = 0.f, acc2 = 0.f, acc3 = 0.f;
  for (int p = s0; p < s1; ++p) {
    int e = eidx[p], s = esrc[p];
    s16x4 ev = *(const s16x4*)(e16 + (size_t)e * 256 + c0);
    s16x4 kv = *(const s16x4*)(K16 + (size_t)s * 256 + c0);
    s16x4 vv = *(const s16x4*)(V16 + (size_t)s * 256 + c0);
    float e0f = b2f((unsigned short)ev[0]), e1f = b2f((unsigned short)ev[1]);
    float e2f = b2f((unsigned short)ev[2]), e3f = b2f((unsigned short)ev[3]);
    float part = q0 * (b2f((unsigned short)kv[0]) + e0f)
               + q1 * (b2f((unsigned short)kv[1]) + e1f)
               + q2 * (b2f((unsigned short)kv[2]) + e2f)
               + q3 * (b2f((unsigned short)kv[3]) + e3f);
    part += __shfl_xor(part, 1);
    part += __shfl_xor(part, 2);
    part += __shfl_xor(part, 4);
    part += __shfl_xor(part, 8);
    part += __shfl_xor(part, 16);    // per-head (32-lane) total
    float ex = __expf(part * INV_SQRT_C);
    den += ex;
    acc0 += ex * (b2f((unsigned short)vv[0]) + e0f);
    acc1 += ex * (b2f((unsigned short)vv[1]) + e1f);
    acc2 += ex * (b2f((unsigned short)vv[2]) + e2f);
    acc3 += ex * (b2f((unsigned short)vv[3]) + e3f);
  }
  float inv = 1.f / (den + 1e-16f);
  float4* op = (float4*)(out + (size_t)d * 256 + c0);
  float4 o = *op;
  o.x += acc0 * inv; o.y += acc1 * inv; o.z += acc2 * inv; o.w += acc3 * inv;
  *op = o;
}

extern "C" void kernel_launch(void* const* d_in, const int* in_sizes, int n_in,
                              void* d_out, int out_size, void* d_ws, size_t ws_size,
                              hipStream_t stream) {
  const float* x_user  = (const float*)d_in[0];
  const float* x_item  = (const float*)d_in[1];
  const float* lu_user = (const float*)d_in[2];
  const float* lu_item = (const float*)d_in[3];
  const int*   ei_a    = (const int*)d_in[4];
  const int*   ei_b    = (const int*)d_in[5];
  const float* t_a     = (const float*)d_in[6];
  const float* t_b     = (const float*)d_in[7];
  const float* msg_a   = (const float*)d_in[8];
  const float* msg_b   = (const float*)d_in[9];
  const float* W_t     = (const float*)d_in[10];
  const float* b_t     = (const float*)d_in[11];
  const float* Wq_a = (const float*)d_in[12]; const float* bq_a = (const float*)d_in[13];
  const float* Wk_a = (const float*)d_in[14]; const float* bk_a = (const float*)d_in[15];
  const float* Wv_a = (const float*)d_in[16]; const float* bv_a = (const float*)d_in[17];
  const float* We_a = (const float*)d_in[18];
  const float* Ws_a = (const float*)d_in[19]; const float* bs_a = (const float*)d_in[20];
  const float* Wq_b = (const float*)d_in[21]; const float* bq_b = (const float*)d_in[22];
  const float* Wk_b = (const float*)d_in[23]; const float* bk_b = (const float*)d_in[24];
  const float* Wv_b = (const float*)d_in[25]; const float* bv_b = (const float*)d_in[26];
  const float* We_b = (const float*)d_in[27];
  const float* Ws_b = (const float*)d_in[28]; const float* bs_b = (const float*)d_in[29];

  float* out_user = (float*)d_out;
  float* out_item = (float*)d_out + (size_t)N_NODES * 256;

  WPtrs wp;
  wp.w[0] = Wq_a; wp.w[1] = Wk_a; wp.w[2] = Wv_a; wp.w[3] = Ws_a; wp.w[4] = We_a;
  wp.w[5] = Wq_b; wp.w[6] = Wk_b; wp.w[7] = Wv_b; wp.w[8] = Ws_b; wp.w[9] = We_b;

  dim3 blk(256);
  dim3 blk512(512);
  dim3 gW(40);
  dim3 gN((N_NODES + 63) / 64);
  dim3 gE(E_EDGES / 64);
  dim3 gEt((E_EDGES + 255) / 256);
  dim3 gAgg((N_NODES + 3) / 4);

  // ws layout: ~183 MB (unchanged from round 2/3/4)
  char* ws = (char*)d_ws;
  size_t off = 0;
  short* WtT = (short*)(ws + off); off += (size_t)10 * 65536 * 2;
  unsigned short* Q16 = (unsigned short*)(ws + off); off += (size_t)N_NODES * 256 * 2;
  unsigned short* K16 = (unsigned short*)(ws + off); off += (size_t)N_NODES * 256 * 2;
  unsigned short* V16 = (unsigned short*)(ws + off); off += (size_t)N_NODES * 256 * 2;
  unsigned short* e16 = (unsigned short*)(ws + off); off += (size_t)E_EDGES * 256 * 2;
  int* counts = (int*)(ws + off); off += (size_t)N_NODES * 4;
  int* startb = (int*)(ws + off); off += (size_t)(N_NODES + 4) * 4;
  int* cursor = (int*)(ws + off); off += (size_t)N_NODES * 4;
  int* eidx   = (int*)(ws + off); off += (size_t)E_EDGES * 4;
  int* esrc   = (int*)(ws + off); off += (size_t)E_EDGES * 4;
  if (ws_size < off) return;   // fail loudly (output stays poisoned)

  prep_transpose<<<gW, blk, 0, stream>>>(wp, WtT);

  // ---- type a: user --to--> item (dst=item) ----
  node_gemm3<<<gN, blk512, 0, stream>>>(x_user, N_NODES,
      WtT + 1 * 65536, bk_a, K16, nullptr, WtT + 2 * 65536, bv_a, V16, nullptr);
  node_gemm3<<<gN, blk512, 0, stream>>>(x_item, N_NODES,
      WtT + 0 * 65536, bq_a, Q16, nullptr, WtT + 3 * 65536, bs_a, nullptr, out_item);
  hipMemsetAsync(counts, 0, (size_t)N_NODES * 4, stream);
  csr_count<<<gEt, blk, 0, stream>>>(ei_a, counts);
  csr_scan<<<1, 1024, 0, stream>>>(counts, startb, cursor, N_NODES);
  csr_fill<<<gEt, blk, 0, stream>>>(ei_a, cursor, eidx, esrc);
  edge_gemm3<<<gE, blk512, 0, stream>>>(ei_a, t_a, lu_user, msg_a, W_t, b_t,
      WtT + 4 * 65536, e16);
  aggregate_fused<<<gAgg, blk, 0, stream>>>(startb, eidx, esrc, Q16, K16, V16, e16, out_item);

  // ---- type b: item --rev_to--> user (dst=user) ----
  node_gemm3<<<gN, blk512, 0, stream>>>(x_item, N_NODES,
      WtT + 6 * 65536, bk_b, K16, nullptr, WtT + 7 * 65536, bv_b, V16, nullptr);
  node_gemm3<<<gN, blk512, 0, stream>>>(x_user, N_NODES,
      WtT + 5 * 65536, bq_b, Q16, nullptr, WtT + 8 * 65536, bs_b, nullptr, out_user);
  hipMemsetAsync(counts, 0, (size_t)N_NODES * 4, stream);
  csr_count<<<gEt, blk, 0, stream>>>(ei_b, counts);
  csr_scan<<<1, 1024, 0, stream>>>(counts, startb, cursor, N_NODES);
  csr_fill<<<gEt, blk, 0, stream>>>(ei_b, cursor, eidx, esrc);
  edge_gemm3<<<gE, blk512, 0, stream>>>(ei_b, t_b, lu_item, msg_b, W_t, b_t,
      WtT + 9 * 65536, e16);
  aggregate_fused<<<gAgg, blk, 0, stream>>>(startb, eidx, esrc, Q16, K16, V16, e16, out_user);
}

// Round 6
// 701.106 us; speedup vs baseline: 1.5062x; 1.5062x over previous
//
#include <hip/hip_runtime.h>
#include <hip/hip_bf16.h>

#define N_NODES 50000
#define E_EDGES 200000
static constexpr float INV_SQRT_C = 0.08838834764831845f; // 1/sqrt(128)

typedef __attribute__((ext_vector_type(4))) float f32x4;
typedef __attribute__((ext_vector_type(8))) short s16x8;
typedef __attribute__((ext_vector_type(4))) short s16x4;

__device__ __forceinline__ float b2f(unsigned short u) {
  union { unsigned u; float f; } x; x.u = ((unsigned)u) << 16; return x.f;
}
__device__ __forceinline__ short f2b(float f) {
  union { float f; unsigned u; } x; x.f = f;
  unsigned r = x.u + 0x7FFFu + ((x.u >> 16) & 1u);  // RNE
  return (short)(r >> 16);
}

struct WPtrs { const float* w[10]; };

// Repack 10 [256x256] f32 weights into bf16 MFMA-fragment order:
//   out[((ct*8 + ks)*16 + colb)*32 + g*8 + j] = W[ks*32 + g*8 + j][ct*16 + colb]
// Each (ct,ks) fragment region is a contiguous 1KB block exactly covered by
// one wave's 64 x 16B loads (minimal cache lines).
__global__ __launch_bounds__(256) void prep_transpose(WPtrs p, short* __restrict__ out) {
  __shared__ short T[256 * 66];              // [k][cc], pad 66
  const int wi = blockIdx.x >> 2, cq = blockIdx.x & 3;
  const float* w = p.w[wi];
  short* o = out + wi * 65536;
  const int tid = threadIdx.x;
#pragma unroll
  for (int i = 0; i < 64; ++i) {             // coalesced f32 reads
    int flat = tid + i * 256;
    int k = flat >> 6, cc = flat & 63;
    T[k * 66 + cc] = f2b(w[k * 256 + cq * 64 + cc]);
  }
  __syncthreads();
#pragma unroll
  for (int i = 0; i < 8; ++i) {              // coalesced 16B fragment stores
    int flat2 = tid + i * 256;
    int g = flat2 & 3, colb = (flat2 >> 2) & 15, ks = (flat2 >> 6) & 7, ctl = flat2 >> 9;
    int ct = cq * 4 + ctl;
    s16x8 v;
#pragma unroll
    for (int j = 0; j < 8; ++j)
      v[j] = T[(ks * 32 + g * 8 + j) * 66 + ctl * 16 + colb];
    *(s16x8*)(o + (((ct * 8 + ks) * 16 + colb) * 32 + g * 8)) = v;
  }
}

// ---------------- node GEMM v4 ----------------
// 512 thr / 8 waves, 64 rows per block, wave owns 32 cols (2 ct).
// Inline per-ks B loads (2 loads feed 8 MFMAs) from packed fragment layout.
// NO min-waves launch bound — round 5's (512,4) caused 300MB of VGPR spills.
__global__ __launch_bounds__(512) void node_gemm4(
    const float* __restrict__ X, int M,
    const short* __restrict__ Wt0, const float* __restrict__ bias0,
    unsigned short* __restrict__ o16_0, float* __restrict__ of0,
    const short* __restrict__ Wt1, const float* __restrict__ bias1,
    unsigned short* __restrict__ o16_1, float* __restrict__ of1)
{
  __shared__ short As[64 * 264];
  const int tid = threadIdx.x;
  const int l = tid & 63;
  const int w = tid >> 6;
  const int m0 = blockIdx.x * 64;
  const bool fullblk = (m0 + 64 <= M);

  if (fullblk) {
#pragma unroll
    for (int i = 0; i < 8; ++i) {
      int flat = tid + i * 512;
      int r = flat >> 6, c4 = flat & 63;
      float4 xv = *(const float4*)(X + (size_t)(m0 + r) * 256 + c4 * 4);
      s16x4 sv; sv[0] = f2b(xv.x); sv[1] = f2b(xv.y); sv[2] = f2b(xv.z); sv[3] = f2b(xv.w);
      *(s16x4*)&As[r * 264 + c4 * 4] = sv;
    }
  } else {
#pragma unroll
    for (int i = 0; i < 8; ++i) {
      int flat = tid + i * 512;
      int r = flat >> 6, c4 = flat & 63;
      float4 xv = make_float4(0.f, 0.f, 0.f, 0.f);
      if (m0 + r < M) xv = *(const float4*)(X + (size_t)(m0 + r) * 256 + c4 * 4);
      s16x4 sv; sv[0] = f2b(xv.x); sv[1] = f2b(xv.y); sv[2] = f2b(xv.z); sv[3] = f2b(xv.w);
      *(s16x4*)&As[r * 264 + c4 * 4] = sv;
    }
  }
  __syncthreads();

  const int colb = l & 15;
  const int g = l >> 4;

#pragma unroll 1
  for (int job = 0; job < 2; ++job) {
    const short* Wt = job ? Wt1 : Wt0;
    const float* bias = job ? bias1 : bias0;
    unsigned short* o16 = job ? o16_1 : o16_0;
    float* of = job ? of1 : of0;
    const short* wbase0 = Wt + (((2 * w + 0) * 8) * 16 + colb) * 32 + g * 8;
    const short* wbase1 = Wt + (((2 * w + 1) * 8) * 16 + colb) * 32 + g * 8;

    f32x4 acc[4][2];
#pragma unroll
    for (int m = 0; m < 4; ++m) { acc[m][0] = (f32x4)(0.0f); acc[m][1] = (f32x4)(0.0f); }
#pragma unroll
    for (int ks = 0; ks < 8; ++ks) {
      s16x8 b0 = *(const s16x8*)(wbase0 + ks * 512);
      s16x8 b1 = *(const s16x8*)(wbase1 + ks * 512);
#pragma unroll
      for (int m = 0; m < 4; ++m) {
        s16x8 a = *(const s16x8*)&As[(16 * m + colb) * 264 + ks * 32 + g * 8];
        acc[m][0] = __builtin_amdgcn_mfma_f32_16x16x32_bf16(a, b0, acc[m][0], 0, 0, 0);
        acc[m][1] = __builtin_amdgcn_mfma_f32_16x16x32_bf16(a, b1, acc[m][1], 0, 0, 0);
      }
    }

    if (of) {
#pragma unroll
      for (int j = 0; j < 2; ++j) {
        int col = (2 * w + j) * 16 + colb;
        float bv = bias[col];
#pragma unroll
        for (int m = 0; m < 4; ++m) {
          int rb = m0 + 16 * m + g * 4;
#pragma unroll
          for (int r = 0; r < 4; ++r)
            if (fullblk || rb + r < M) of[(size_t)(rb + r) * 256 + col] = acc[m][j][r] + bv;
        }
      }
    } else {
#pragma unroll
      for (int j = 0; j < 2; ++j) {
        int col = (2 * w + j) * 16 + colb;
        float bv = bias[col];
#pragma unroll
        for (int m = 0; m < 4; ++m) {
          int rb = m0 + 16 * m + g * 4;
#pragma unroll
          for (int r = 0; r < 4; ++r)
            if (fullblk || rb + r < M)
              o16[(size_t)(rb + r) * 256 + col] = (unsigned short)f2b(acc[m][j][r] + bv);
        }
      }
    }
  }
}

// ---------------- CSR build ----------------
__global__ __launch_bounds__(256) void csr_count(const int* __restrict__ ei, int* __restrict__ counts) {
  int t = blockIdx.x * 256 + threadIdx.x;
  if (t < E_EDGES) atomicAdd(&counts[ei[E_EDGES + t]], 1);
}

__global__ __launch_bounds__(1024) void csr_scan(const int* __restrict__ counts,
                                                 int* __restrict__ start,
                                                 int* __restrict__ cursor, int n) {
  __shared__ int wsum[16];
  __shared__ int chunk_tot;
  __shared__ int carry_s;
  const int tid = threadIdx.x, lane = tid & 63, wid = tid >> 6;
  if (tid == 0) carry_s = 0;
  __syncthreads();
  for (int base = 0; base < n; base += 1024) {
    int gi = base + tid;
    int x = (gi < n) ? counts[gi] : 0;
    int v = x;
#pragma unroll
    for (int d = 1; d < 64; d <<= 1) {
      int t = __shfl_up(v, d);
      if (lane >= d) v += t;
    }
    if (lane == 63) wsum[wid] = v;
    __syncthreads();
    if (tid == 0) {
      int run = 0;
#pragma unroll
      for (int i = 0; i < 16; ++i) { int t = wsum[i]; wsum[i] = run; run += t; }
      chunk_tot = run;
    }
    __syncthreads();
    if (gi < n) {
      int excl = carry_s + wsum[wid] + v - x;
      start[gi] = excl;
      cursor[gi] = excl;
    }
    __syncthreads();
    if (tid == 0) carry_s += chunk_tot;
  }
  if (tid == 0) start[n] = carry_s;
}

__global__ __launch_bounds__(256) void csr_fill(const int* __restrict__ ei,
                                                int* __restrict__ cursor,
                                                int* __restrict__ eidx, int* __restrict__ esrc) {
  int t = blockIdx.x * 256 + threadIdx.x;
  if (t < E_EDGES) {
    int d = ei[E_EDGES + t];
    int p = atomicAdd(&cursor[d], 1);
    eidx[p] = t;
    esrc[p] = ei[t];
  }
}

// ---------------- edge GEMM v4: e16 = [cos(rel*Wt+bt) | msg] @ We ----------------
__global__ __launch_bounds__(512) void edge_gemm4(
    const int* __restrict__ ei, const float* __restrict__ tvec,
    const float* __restrict__ lu, const float* __restrict__ msg,
    const float* __restrict__ Wtim, const float* __restrict__ btim,
    const short* __restrict__ WeT, unsigned short* __restrict__ e16g)
{
  __shared__ short attr[64 * 264];
  __shared__ float rel[64];

  const int tid = threadIdx.x;
  const int l = tid & 63;
  const int w = tid >> 6;
  const int e0 = blockIdx.x * 64;
  const int colb = l & 15;
  const int g = l >> 4;

  const float wt = Wtim[tid & 127], bt = btim[tid & 127];

  if (tid < 64) rel[tid] = tvec[e0 + tid] - lu[ei[e0 + tid]];
#pragma unroll
  for (int i = 0; i < 4; ++i) {
    int flat = tid + i * 512;
    int row = flat >> 5, c4 = flat & 31;
    float4 mv = *(const float4*)(msg + (size_t)(e0 + row) * 128 + c4 * 4);
    s16x4 sv; sv[0] = f2b(mv.x); sv[1] = f2b(mv.y); sv[2] = f2b(mv.z); sv[3] = f2b(mv.w);
    *(s16x4*)&attr[row * 264 + 128 + c4 * 4] = sv;
  }
  __syncthreads();   // rel + msg staged

  { // time-encoder cols: fixed col per thread, 16 rows each
    int col = tid & 127;
    int r0 = (tid >> 7) * 16;
#pragma unroll
    for (int i = 0; i < 16; ++i)
      attr[(r0 + i) * 264 + col] = f2b(__cosf(rel[r0 + i] * wt + bt));
  }
  __syncthreads();

  const short* wbase0 = WeT + (((2 * w + 0) * 8) * 16 + colb) * 32 + g * 8;
  const short* wbase1 = WeT + (((2 * w + 1) * 8) * 16 + colb) * 32 + g * 8;
  f32x4 acc[4][2];
#pragma unroll
  for (int m = 0; m < 4; ++m) { acc[m][0] = (f32x4)(0.0f); acc[m][1] = (f32x4)(0.0f); }
#pragma unroll
  for (int ks = 0; ks < 8; ++ks) {
    s16x8 b0 = *(const s16x8*)(wbase0 + ks * 512);
    s16x8 b1 = *(const s16x8*)(wbase1 + ks * 512);
#pragma unroll
    for (int m = 0; m < 4; ++m) {
      s16x8 a = *(const s16x8*)&attr[(16 * m + colb) * 264 + ks * 32 + g * 8];
      acc[m][0] = __builtin_amdgcn_mfma_f32_16x16x32_bf16(a, b0, acc[m][0], 0, 0, 0);
      acc[m][1] = __builtin_amdgcn_mfma_f32_16x16x32_bf16(a, b1, acc[m][1], 0, 0, 0);
    }
  }
  __syncthreads();   // all waves done reading attr
#pragma unroll
  for (int j = 0; j < 2; ++j)
#pragma unroll
    for (int m = 0; m < 4; ++m)
#pragma unroll
      for (int r = 0; r < 4; ++r)
        attr[(16 * m + g * 4 + r) * 264 + (2 * w + j) * 16 + colb] = f2b(acc[m][j][r]);
  __syncthreads();

  // stream e (bf16) to global, coalesced 16B stores
#pragma unroll
  for (int i = 0; i < 4; ++i) {
    int flat = tid + i * 512;
    int row = flat >> 5, cg = flat & 31;
    *(s16x8*)(e16g + (size_t)(e0 + row) * 256 + cg * 8) = *(const s16x8*)&attr[row * 264 + cg * 8];
  }
}

// ---------------- fused aggregate: one wave per dst node ----------------
__global__ __launch_bounds__(256) void aggregate_fused(
    const int* __restrict__ start, const int* __restrict__ eidx, const int* __restrict__ esrc,
    const unsigned short* __restrict__ Q16, const unsigned short* __restrict__ K16,
    const unsigned short* __restrict__ V16, const unsigned short* __restrict__ e16,
    float* __restrict__ out)
{
  const int d = blockIdx.x * 4 + (threadIdx.x >> 6);
  if (d >= N_NODES) return;
  const int lane = threadIdx.x & 63;
  const int s0 = start[d], s1 = start[d + 1];
  if (s1 <= s0) return;
  const int c0 = lane * 4;          // lanes 0-31: head 0; 32-63: head 1

  s16x4 qv = *(const s16x4*)(Q16 + (size_t)d * 256 + c0);
  const float q0 = b2f((unsigned short)qv[0]), q1 = b2f((unsigned short)qv[1]);
  const float q2 = b2f((unsigned short)qv[2]), q3 = b2f((unsigned short)qv[3]);

  float den = 0.f;
  float acc0 = 0.f, acc1 = 0.f, acc2 = 0.f, acc3 = 0.f;
  for (int p = s0; p < s1; ++p) {
    int e = eidx[p], s = esrc[p];
    s16x4 ev = *(const s16x4*)(e16 + (size_t)e * 256 + c0);
    s16x4 kv = *(const s16x4*)(K16 + (size_t)s * 256 + c0);
    s16x4 vv = *(const s16x4*)(V16 + (size_t)s * 256 + c0);
    float e0f = b2f((unsigned short)ev[0]), e1f = b2f((unsigned short)ev[1]);
    float e2f = b2f((unsigned short)ev[2]), e3f = b2f((unsigned short)ev[3]);
    float part = q0 * (b2f((unsigned short)kv[0]) + e0f)
               + q1 * (b2f((unsigned short)kv[1]) + e1f)
               + q2 * (b2f((unsigned short)kv[2]) + e2f)
               + q3 * (b2f((unsigned short)kv[3]) + e3f);
    part += __shfl_xor(part, 1);
    part += __shfl_xor(part, 2);
    part += __shfl_xor(part, 4);
    part += __shfl_xor(part, 8);
    part += __shfl_xor(part, 16);    // per-head (32-lane) total
    float ex = __expf(part * INV_SQRT_C);
    den += ex;
    acc0 += ex * (b2f((unsigned short)vv[0]) + e0f);
    acc1 += ex * (b2f((unsigned short)vv[1]) + e1f);
    acc2 += ex * (b2f((unsigned short)vv[2]) + e2f);
    acc3 += ex * (b2f((unsigned short)vv[3]) + e3f);
  }
  float inv = 1.f / (den + 1e-16f);
  float4* op = (float4*)(out + (size_t)d * 256 + c0);
  float4 o = *op;
  o.x += acc0 * inv; o.y += acc1 * inv; o.z += acc2 * inv; o.w += acc3 * inv;
  *op = o;
}

extern "C" void kernel_launch(void* const* d_in, const int* in_sizes, int n_in,
                              void* d_out, int out_size, void* d_ws, size_t ws_size,
                              hipStream_t stream) {
  const float* x_user  = (const float*)d_in[0];
  const float* x_item  = (const float*)d_in[1];
  const float* lu_user = (const float*)d_in[2];
  const float* lu_item = (const float*)d_in[3];
  const int*   ei_a    = (const int*)d_in[4];
  const int*   ei_b    = (const int*)d_in[5];
  const float* t_a     = (const float*)d_in[6];
  const float* t_b     = (const float*)d_in[7];
  const float* msg_a   = (const float*)d_in[8];
  const float* msg_b   = (const float*)d_in[9];
  const float* W_t     = (const float*)d_in[10];
  const float* b_t     = (const float*)d_in[11];
  const float* Wq_a = (const float*)d_in[12]; const float* bq_a = (const float*)d_in[13];
  const float* Wk_a = (const float*)d_in[14]; const float* bk_a = (const float*)d_in[15];
  const float* Wv_a = (const float*)d_in[16]; const float* bv_a = (const float*)d_in[17];
  const float* We_a = (const float*)d_in[18];
  const float* Ws_a = (const float*)d_in[19]; const float* bs_a = (const float*)d_in[20];
  const float* Wq_b = (const float*)d_in[21]; const float* bq_b = (const float*)d_in[22];
  const float* Wk_b = (const float*)d_in[23]; const float* bk_b = (const float*)d_in[24];
  const float* Wv_b = (const float*)d_in[25]; const float* bv_b = (const float*)d_in[26];
  const float* We_b = (const float*)d_in[27];
  const float* Ws_b = (const float*)d_in[28]; const float* bs_b = (const float*)d_in[29];

  float* out_user = (float*)d_out;
  float* out_item = (float*)d_out + (size_t)N_NODES * 256;

  WPtrs wp;
  wp.w[0] = Wq_a; wp.w[1] = Wk_a; wp.w[2] = Wv_a; wp.w[3] = Ws_a; wp.w[4] = We_a;
  wp.w[5] = Wq_b; wp.w[6] = Wk_b; wp.w[7] = Wv_b; wp.w[8] = Ws_b; wp.w[9] = We_b;

  dim3 blk(256);
  dim3 blk512(512);
  dim3 gW(40);
  dim3 gN((N_NODES + 63) / 64);
  dim3 gE(E_EDGES / 64);
  dim3 gEt((E_EDGES + 255) / 256);
  dim3 gAgg((N_NODES + 3) / 4);

  // ws layout: ~183 MB (unchanged)
  char* ws = (char*)d_ws;
  size_t off = 0;
  short* WtT = (short*)(ws + off); off += (size_t)10 * 65536 * 2;
  unsigned short* Q16 = (unsigned short*)(ws + off); off += (size_t)N_NODES * 256 * 2;
  unsigned short* K16 = (unsigned short*)(ws + off); off += (size_t)N_NODES * 256 * 2;
  unsigned short* V16 = (unsigned short*)(ws + off); off += (size_t)N_NODES * 256 * 2;
  unsigned short* e16 = (unsigned short*)(ws + off); off += (size_t)E_EDGES * 256 * 2;
  int* counts = (int*)(ws + off); off += (size_t)N_NODES * 4;
  int* startb = (int*)(ws + off); off += (size_t)(N_NODES + 4) * 4;
  int* cursor = (int*)(ws + off); off += (size_t)N_NODES * 4;
  int* eidx   = (int*)(ws + off); off += (size_t)E_EDGES * 4;
  int* esrc   = (int*)(ws + off); off += (size_t)E_EDGES * 4;
  if (ws_size < off) return;   // fail loudly (output stays poisoned)

  prep_transpose<<<gW, blk, 0, stream>>>(wp, WtT);

  // ---- type a: user --to--> item (dst=item) ----
  node_gemm4<<<gN, blk512, 0, stream>>>(x_user, N_NODES,
      WtT + 1 * 65536, bk_a, K16, nullptr, WtT + 2 * 65536, bv_a, V16, nullptr);
  node_gemm4<<<gN, blk512, 0, stream>>>(x_item, N_NODES,
      WtT + 0 * 65536, bq_a, Q16, nullptr, WtT + 3 * 65536, bs_a, nullptr, out_item);
  hipMemsetAsync(counts, 0, (size_t)N_NODES * 4, stream);
  csr_count<<<gEt, blk, 0, stream>>>(ei_a, counts);
  csr_scan<<<1, 1024, 0, stream>>>(counts, startb, cursor, N_NODES);
  csr_fill<<<gEt, blk, 0, stream>>>(ei_a, cursor, eidx, esrc);
  edge_gemm4<<<gE, blk512, 0, stream>>>(ei_a, t_a, lu_user, msg_a, W_t, b_t,
      WtT + 4 * 65536, e16);
  aggregate_fused<<<gAgg, blk, 0, stream>>>(startb, eidx, esrc, Q16, K16, V16, e16, out_item);

  // ---- type b: item --rev_to--> user (dst=user) ----
  node_gemm4<<<gN, blk512, 0, stream>>>(x_item, N_NODES,
      WtT + 6 * 65536, bk_b, K16, nullptr, WtT + 7 * 65536, bv_b, V16, nullptr);
  node_gemm4<<<gN, blk512, 0, stream>>>(x_user, N_NODES,
      WtT + 5 * 65536, bq_b, Q16, nullptr, WtT + 8 * 65536, bs_b, nullptr, out_user);
  hipMemsetAsync(counts, 0, (size_t)N_NODES * 4, stream);
  csr_count<<<gEt, blk, 0, stream>>>(ei_b, counts);
  csr_scan<<<1, 1024, 0, stream>>>(counts, startb, cursor, N_NODES);
  csr_fill<<<gEt, blk, 0, stream>>>(ei_b, cursor, eidx, esrc);
  edge_gemm4<<<gE, blk512, 0, stream>>>(ei_b, t_b, lu_item, msg_b, W_t, b_t,
      WtT + 9 * 65536, e16);
  aggregate_fused<<<gAgg, blk, 0, stream>>>(startb, eidx, esrc, Q16, K16, V16, e16, out_user);
}